// Round 8
// baseline (482.197 us; speedup 1.0000x reference)
//
#include <hip/hip_runtime.h>
#include <math.h>

#define N_NODES 10000
#define FEAT 512
#define HID 256
#define EMB 128
#define NC 10
#define NE_EDGES 160000
#define KTOP 10
#define NNB 9

#define CAP 128          // per-row candidate buffer capacity
#define NSEL 16          // candidates f64-rescored
#define TAU 0.11f        // store threshold (sims ~ N(0,0.0442), s10 ~ 0.19)
#define SAFE_VAL 0.12f   // need >=10 stored above this, else fallback
#define NTB 79           // 79 tiles of 128
#define NPAIR 3160       // 79*80/2 upper-triangle blocks

typedef __attribute__((ext_vector_type(8))) short short8;
typedef __attribute__((ext_vector_type(4))) float f32x4;

typedef const __attribute__((address_space(1))) unsigned int* gas1_t;
typedef __attribute__((address_space(3))) unsigned int* las3_t;

__device__ __forceinline__ void gload_lds16(const void* g, void* l) {
  __builtin_amdgcn_global_load_lds((gas1_t)g, (las3_t)l, 16, 0, 0);
}

__device__ __forceinline__ unsigned short f2h(float f) {
  _Float16 h = (_Float16)f;
  return *(unsigned short*)&h;
}
__device__ __forceinline__ float h2f(unsigned short u) {
  _Float16 h = *(_Float16*)&u;
  return (float)h;
}

// -------------------- row norms -> f16 normalized + f16 raw + f64 inv norms --------------------
__global__ void k_norms(const float* __restrict__ x, unsigned short* __restrict__ xnf,
                        unsigned short* __restrict__ xf, double* __restrict__ rinv) {
  const int row = blockIdx.x;
  const int t = threadIdx.x;  // 128
  const float* xr = x + (size_t)row * FEAT;
  double s = 0.0;
  for (int k = t; k < FEAT; k += 128) { const double v = (double)xr[k]; s += v * v; }
  __shared__ double red[128];
  red[t] = s;
  __syncthreads();
  for (int o = 64; o > 0; o >>= 1) {
    if (t < o) red[t] += red[t + o];
    __syncthreads();
  }
  const double inv = 1.0 / fmax(sqrt(red[0]), 1e-12);
  const float finv = (float)inv;
  for (int k = t; k < FEAT; k += 128) {
    const float v = xr[k];
    xnf[(size_t)row * FEAT + k] = f2h(v * finv);
    xf[(size_t)row * FEAT + k] = f2h(v);
  }
  if (t == 0) rinv[row] = inv;
}

// -------------------- weight transpose + f16: Wt[n][k] = W[k][n] --------------------
__global__ void k_wt(const float* __restrict__ W, unsigned short* __restrict__ Wt, int K, int N) {
  const int idx = blockIdx.x * 256 + threadIdx.x;
  if (idx < K * N) {
    const int n = idx / K, k = idx % K;
    Wt[idx] = f2h(W[(size_t)k * N + n]);
  }
}

// -------------------- sim GEMM (upper triangle) + threshold filter --------------------
// 3-stage LDS ring, depth-2 prefetch: tile kt+2 issued at iter kt; vmcnt(8) waits for the
// oldest stage (12 loads max in flight, 4/stage/thread). 48KB LDS -> 3 blocks/CU.
__global__ __launch_bounds__(256) void k_simgemm(const unsigned short* __restrict__ xnf,
                                                 unsigned int* __restrict__ cap_buf,
                                                 int* __restrict__ cnt_row) {
  __shared__ __align__(16) unsigned short As[3][4096];
  __shared__ __align__(16) unsigned short Bs[3][4096];

  const int t = threadIdx.x;
  const int lane = t & 63;
  const int w = t >> 6;
  const int lr = lane & 15;
  const int lk = lane >> 4;
  const int wr = (w >> 1) * 64, wc = (w & 1) * 64;

  // XCD-chunked bijective remap (3160 = 8*395), then triangular decode (bi <= bj)
  const int bid = (blockIdx.x & 7) * 395 + (blockIdx.x >> 3);
  int bi = (int)((159.0 - sqrt(25281.0 - 8.0 * (double)bid)) * 0.5);
  while ((bi + 1) * NTB - (bi + 1) * bi / 2 <= bid) ++bi;
  while (bi * NTB - bi * (bi - 1) / 2 > bid) --bi;
  const int bj = bi + (bid - (bi * NTB - bi * (bi - 1) / 2));
  const int arow0 = bi * 128;
  const int bcol0 = bj * 128;

  auto stage = [&](int s, int k0) {
#pragma unroll
    for (int it = 0; it < 2; ++it) {
      const int slot = it * 256 + w * 64 + lane;
      const int r = slot >> 2;
      const int qs = (slot & 3) ^ ((slot >> 3) & 3);  // source swizzle
      {
        const int gr = min(arow0 + r, N_NODES - 1);
        gload_lds16(xnf + (size_t)gr * FEAT + k0 + qs * 8, &As[s][(it * 256 + w * 64) * 8]);
      }
      {
        const int gc = min(bcol0 + r, N_NODES - 1);
        gload_lds16(xnf + (size_t)gc * FEAT + k0 + qs * 8, &Bs[s][(it * 256 + w * 64) * 8]);
      }
    }
  };

  f32x4 acc[4][4];
#pragma unroll
  for (int m = 0; m < 4; ++m)
#pragma unroll
    for (int n = 0; n < 4; ++n) acc[m][n] = (f32x4){0.f, 0.f, 0.f, 0.f};

  stage(0, 0);
  stage(1, 32);

  const int NT = FEAT / 32;  // 16
  int cur = 0, nxt = 2;
  for (int kt = 0; kt < NT; ++kt) {
    if (kt + 2 < NT) {
      stage(nxt, (kt + 2) * 32);
      asm volatile("s_waitcnt vmcnt(8)" ::: "memory");
    } else if (kt + 1 < NT) {
      asm volatile("s_waitcnt vmcnt(4)" ::: "memory");
    } else {
      asm volatile("s_waitcnt vmcnt(0)" ::: "memory");
    }
    __builtin_amdgcn_sched_barrier(0);
    __builtin_amdgcn_s_barrier();
    const unsigned short* Ab = As[cur];
    const unsigned short* Bb = Bs[cur];
    short8 a[4], b[4];
#pragma unroll
    for (int m = 0; m < 4; ++m) {
      const int row = wr + m * 16 + lr;
      a[m] = *(const short8*)(Ab + (((row << 2) | (lk ^ ((row >> 1) & 3))) << 3));
    }
#pragma unroll
    for (int n = 0; n < 4; ++n) {
      const int row = wc + n * 16 + lr;
      b[n] = *(const short8*)(Bb + (((row << 2) | (lk ^ ((row >> 1) & 3))) << 3));
    }
    __builtin_amdgcn_s_setprio(1);
#pragma unroll
    for (int m = 0; m < 4; ++m)
#pragma unroll
      for (int n = 0; n < 4; ++n)
        acc[m][n] = __builtin_amdgcn_mfma_f32_16x16x32_f16(a[m], b[n], acc[m][n], 0, 0, 0);
    __builtin_amdgcn_s_setprio(0);
    asm volatile("" ::: "memory");
    if (kt + 1 < NT) __builtin_amdgcn_s_barrier();
    cur = (cur == 2) ? 0 : cur + 1;
    nxt = (nxt == 2) ? 0 : nxt + 1;
  }

  // filter epilogue. C/D layout: col = lane&15, row = (lane>>4)*4 + reg
  const bool offdiag = (bi != bj);
#pragma unroll
  for (int m = 0; m < 4; ++m) {
    const int rb = arow0 + wr + m * 16 + lk * 4;
#pragma unroll
    for (int n = 0; n < 4; ++n) {
      const int gc = bcol0 + wc + n * 16 + lr;
      if (gc < N_NODES) {
#pragma unroll
        for (int q = 0; q < 4; ++q) {
          const float v = acc[m][n][q];
          const int gr = rb + q;
          if (v > TAU && gr < N_NODES) {
            const unsigned short hv = f2h(v);
            {
              const int pos = atomicAdd(&cnt_row[gr], 1);
              if (pos < CAP)
                cap_buf[(size_t)gr * CAP + pos] = ((unsigned)hv << 16) | (unsigned)gc;
            }
            if (offdiag) {
              const int pos = atomicAdd(&cnt_row[gc], 1);
              if (pos < CAP)
                cap_buf[(size_t)gc * CAP + pos] = ((unsigned)hv << 16) | (unsigned)gr;
            }
          }
        }
      }
    }
  }
}

// -------------------- fused select + exact f64 rescore -> 9 neighbors (set semantics) --------------------
__global__ __launch_bounds__(256) void k_knn(const float* __restrict__ x,
                                             const double* __restrict__ rinv,
                                             const unsigned int* __restrict__ cap_buf,
                                             const int* __restrict__ cnt_row,
                                             int* __restrict__ nb, int* __restrict__ flags) {
  const int i = blockIdx.x;
  const int t = threadIdx.x;
  const int lane = t & 63;
  const int wave = t >> 6;
  __shared__ unsigned pp[CAP];
  __shared__ int sel[NSEL];
  __shared__ float xi[FEAT];
  __shared__ double dsv[NSEL];
  __shared__ int safe_cnt;

  const int cnt = cnt_row[i];
  if (cnt > CAP || cnt < NSEL) {
    if (t == 0) flags[i] = 1;
    return;
  }
  if (t == 0) { flags[i] = 0; safe_cnt = 0; }
  const int L = cnt;
  if (t < L) pp[t] = cap_buf[(size_t)i * CAP + t];
  xi[t] = x[(size_t)i * FEAT + t];
  xi[t + 256] = x[(size_t)i * FEAT + t + 256];
  __syncthreads();

  if (t < L) {
    const unsigned p = pp[t];
    if (h2f((unsigned short)(p >> 16)) >= SAFE_VAL) atomicAdd(&safe_cnt, 1);
    int rk = 0;
    for (int j = 0; j < L; ++j) rk += (pp[j] > p);
    if (rk < NSEL) sel[rk] = (int)(p & 0xffffu);
  }
  __syncthreads();
  if (safe_cnt < KTOP) {
    if (t == 0) flags[i] = 1;
    return;
  }

  const double ri = rinv[i];
  const float4 v0 = *(const float4*)(xi + lane * 8);
  const float4 v1 = *(const float4*)(xi + lane * 8 + 4);
#pragma unroll
  for (int q = 0; q < 4; ++q) {
    const int c = wave * 4 + q;
    const int ci = sel[c];
    const float4* xr = (const float4*)(x + (size_t)ci * FEAT);
    const float4 u0 = xr[lane * 2];
    const float4 u1 = xr[lane * 2 + 1];
    double s = (double)u0.x * (double)v0.x + (double)u0.y * (double)v0.y +
               (double)u0.z * (double)v0.z + (double)u0.w * (double)v0.w +
               (double)u1.x * (double)v1.x + (double)u1.y * (double)v1.y +
               (double)u1.z * (double)v1.z + (double)u1.w * (double)v1.w;
#pragma unroll
    for (int off = 1; off < 64; off <<= 1) s += __shfl_xor(s, off);
    if (lane == 0) dsv[c] = s * ri * rinv[ci];
  }
  __syncthreads();

  if (t < NSEL) {
    const double v = dsv[t];
    const int id = sel[t];
    int rk = 0;
    for (int j = 0; j < NSEL; ++j)
      rk += (dsv[j] > v) || (dsv[j] == v && sel[j] < id);
    if (rk >= 1 && rk < KTOP) nb[(size_t)i * NNB + (rk - 1)] = id;
  }
}

// -------------------- fallback: exact full scan for flagged rows (expected: none) --------------------
__global__ __launch_bounds__(256) void k_fallback(const float* __restrict__ x,
                                                  const double* __restrict__ rinv,
                                                  const int* __restrict__ flags,
                                                  int* __restrict__ nb) {
  const int i = blockIdx.x;
  if (!flags[i]) return;
  const int t = threadIdx.x;
  __shared__ float xi[FEAT];
  __shared__ double cval[256];
  __shared__ double bestv[NNB];
  __shared__ int besti[NNB];
  for (int k = t; k < FEAT; k += 256) xi[k] = x[(size_t)i * FEAT + k];
  if (t < NNB) { bestv[t] = -1e300; besti[t] = 0x7fffffff; }
  __syncthreads();
  const double ri = rinv[i];
  for (int c0 = 0; c0 < N_NODES; c0 += 256) {
    const int c = c0 + t;
    double s = -1e300;
    if (c < N_NODES && c != i) {
      s = 0.0;
      for (int k = 0; k < FEAT; ++k) s += (double)xi[k] * (double)x[(size_t)c * FEAT + k];
      s *= ri * rinv[c];
    }
    cval[t] = s;
    __syncthreads();
    if (t == 0) {
      for (int j = 0; j < 256; ++j) {
        const int c2 = c0 + j;
        const double v = cval[j];
        if (v == -1e300) continue;
        int pos = NNB;
        for (int q = 0; q < NNB; ++q) {
          if (v > bestv[q] || (v == bestv[q] && c2 < besti[q])) { pos = q; break; }
        }
        if (pos < NNB) {
          for (int q = NNB - 1; q > pos; --q) { bestv[q] = bestv[q - 1]; besti[q] = besti[q - 1]; }
          bestv[pos] = v; besti[pos] = c2;
        }
      }
    }
    __syncthreads();
  }
  if (t < NNB) nb[(size_t)i * NNB + t] = besti[t];
}

// -------------------- CSR build helpers --------------------
__global__ void k_zero(int* __restrict__ p, int n) {
  const int i = blockIdx.x * blockDim.x + threadIdx.x;
  if (i < n) p[i] = 0;
}

__global__ void k_count(const int* __restrict__ dsts, int ne, int* __restrict__ cnt) {
  const int e = blockIdx.x * blockDim.x + threadIdx.x;
  if (e < ne) atomicAdd(&cnt[dsts[e]], 1);
}

__global__ void k_scan(const int* __restrict__ cnt, int n, int* __restrict__ off,
                       int* __restrict__ cur, float* __restrict__ dinv) {
  __shared__ int buf[1024];
  __shared__ int base_s;
  const int t = threadIdx.x;
  if (t == 0) base_s = 0;
  __syncthreads();
  for (int b0 = 0; b0 < n; b0 += 1024) {
    const int i = b0 + t;
    const int v = (i < n) ? cnt[i] : 0;
    buf[t] = v;
    __syncthreads();
    for (int o = 1; o < 1024; o <<= 1) {
      const int add = (t >= o) ? buf[t - o] : 0;
      __syncthreads();
      buf[t] += add;
      __syncthreads();
    }
    const int incl = buf[t];
    const int base = base_s;
    if (i < n) {
      const int excl = base + incl - v;
      off[i] = excl;
      cur[i] = excl;
      dinv[i] = rsqrtf((float)(v + 1));
    }
    __syncthreads();
    if (t == 1023) base_s = base + buf[1023];
    __syncthreads();
  }
  if (t == 0) off[n] = base_s;
}

__global__ void k_scatter_s(const int* __restrict__ src, const int* __restrict__ dst, int ne,
                            int* __restrict__ cur, int* __restrict__ csr) {
  const int e = blockIdx.x * blockDim.x + threadIdx.x;
  if (e < ne) {
    const int p = atomicAdd(&cur[dst[e]], 1);
    csr[p] = src[e];
  }
}

__global__ void k_scatter_t(const int* __restrict__ nb, int* __restrict__ cur,
                            int* __restrict__ csr) {
  const int e = blockIdx.x * blockDim.x + threadIdx.x;
  if (e < N_NODES * NNB) {
    const int i = e / NNB;
    const int v = nb[e];
    const int p = atomicAdd(&cur[v], 1);
    csr[p] = i;
  }
}

// -------------------- f16 MFMA feature GEMM (merged pair), 3-stage ring --------------------
__global__ __launch_bounds__(256) void k_fgemm2(const unsigned short* __restrict__ A0,
                                                const unsigned short* __restrict__ A1,
                                                const unsigned short* __restrict__ Bt0,
                                                const unsigned short* __restrict__ Bt1,
                                                float* __restrict__ C0, float* __restrict__ C1,
                                                int M, int K, int N) {
  __shared__ __align__(16) unsigned short As[3][4096];
  __shared__ __align__(16) unsigned short Bs[3][4096];
  const int t = threadIdx.x;
  const int lane = t & 63, w = t >> 6;
  const int lr = lane & 15, lk = lane >> 4;
  const int wr = (w >> 1) * 64, wc = (w & 1) * 64;
  const int nbn = N >> 7;
  const int half = blockIdx.y / nbn;
  const unsigned short* A = half ? A1 : A0;
  const unsigned short* Bt = half ? Bt1 : Bt0;
  float* C = half ? C1 : C0;
  const int arow0 = blockIdx.x * 128, bcol0 = (blockIdx.y % nbn) * 128;

  auto stage = [&](int s, int k0) {
#pragma unroll
    for (int it = 0; it < 2; ++it) {
      const int slot = it * 256 + w * 64 + lane;
      const int r = slot >> 2;
      const int qs = (slot & 3) ^ ((slot >> 3) & 3);
      {
        const int gr = min(arow0 + r, M - 1);
        gload_lds16(A + (size_t)gr * K + k0 + qs * 8, &As[s][(it * 256 + w * 64) * 8]);
      }
      {
        const int gc = min(bcol0 + r, N - 1);
        gload_lds16(Bt + (size_t)gc * K + k0 + qs * 8, &Bs[s][(it * 256 + w * 64) * 8]);
      }
    }
  };

  f32x4 acc[4][4];
#pragma unroll
  for (int m = 0; m < 4; ++m)
#pragma unroll
    for (int n = 0; n < 4; ++n) acc[m][n] = (f32x4){0.f, 0.f, 0.f, 0.f};

  stage(0, 0);
  if (K > 32) stage(1, 32);

  const int NT = K >> 5;
  int cur = 0, nxt = 2;
  for (int kt = 0; kt < NT; ++kt) {
    if (kt + 2 < NT) {
      stage(nxt, (kt + 2) << 5);
      asm volatile("s_waitcnt vmcnt(8)" ::: "memory");
    } else if (kt + 1 < NT) {
      asm volatile("s_waitcnt vmcnt(4)" ::: "memory");
    } else {
      asm volatile("s_waitcnt vmcnt(0)" ::: "memory");
    }
    __builtin_amdgcn_sched_barrier(0);
    __builtin_amdgcn_s_barrier();
    const unsigned short* Ab = As[cur];
    const unsigned short* Bb = Bs[cur];
    short8 a[4], b[4];
#pragma unroll
    for (int m = 0; m < 4; ++m) {
      const int row = wr + m * 16 + lr;
      a[m] = *(const short8*)(Ab + (((row << 2) | (lk ^ ((row >> 1) & 3))) << 3));
    }
#pragma unroll
    for (int n = 0; n < 4; ++n) {
      const int row = wc + n * 16 + lr;
      b[n] = *(const short8*)(Bb + (((row << 2) | (lk ^ ((row >> 1) & 3))) << 3));
    }
    __builtin_amdgcn_s_setprio(1);
#pragma unroll
    for (int m = 0; m < 4; ++m)
#pragma unroll
      for (int n = 0; n < 4; ++n)
        acc[m][n] = __builtin_amdgcn_mfma_f32_16x16x32_f16(a[m], b[n], acc[m][n], 0, 0, 0);
    __builtin_amdgcn_s_setprio(0);
    asm volatile("" ::: "memory");
    if (kt + 1 < NT) __builtin_amdgcn_s_barrier();
    cur = (cur == 2) ? 0 : cur + 1;
    nxt = (nxt == 2) ? 0 : nxt + 1;
  }

#pragma unroll
  for (int m = 0; m < 4; ++m) {
    const int rb = arow0 + wr + m * 16 + lk * 4;
#pragma unroll
    for (int n = 0; n < 4; ++n) {
      const int gc = bcol0 + wc + n * 16 + lr;
#pragma unroll
      for (int q = 0; q < 4; ++q) {
        const int gm = rb + q;
        if (gm < M) C[(size_t)gm * N + gc] = acc[m][n][q];
      }
    }
  }
}

// -------------------- GCN aggregation (f32 in, f16 out, relu), 2-way unrolled --------------------
__global__ void k_agg_h(const float* __restrict__ h, const float* __restrict__ bias,
                        const float* __restrict__ dinv, const int* __restrict__ off,
                        const int* __restrict__ csr, unsigned short* __restrict__ out) {
  const int v = blockIdx.x;
  const int c = threadIdx.x;  // HID
  const float dv = dinv[v];
  float acc = h[(size_t)v * HID + c] * dv;
  const int s0 = off[v], s1 = off[v + 1];
  int e = s0;
  for (; e + 1 < s1; e += 2) {
    const int sa = csr[e], sb = csr[e + 1];
    const float ha = h[(size_t)sa * HID + c], hb = h[(size_t)sb * HID + c];
    acc += ha * dinv[sa] + hb * dinv[sb];
  }
  if (e < s1) {
    const int sa = csr[e];
    acc += h[(size_t)sa * HID + c] * dinv[sa];
  }
  acc = acc * dv + bias[c];
  out[(size_t)v * HID + c] = f2h(fmaxf(acc, 0.f));
}

// -------------------- GCN aggregation (f32 in/out), 2-way unrolled --------------------
__global__ void k_agg(const float* __restrict__ h, const float* __restrict__ bias,
                      const float* __restrict__ dinv, const int* __restrict__ off,
                      const int* __restrict__ csr, float* __restrict__ out) {
  const int v = blockIdx.x;
  const int c = threadIdx.x;  // EMB
  const float dv = dinv[v];
  float acc = h[(size_t)v * EMB + c] * dv;
  const int s0 = off[v], s1 = off[v + 1];
  int e = s0;
  for (; e + 1 < s1; e += 2) {
    const int sa = csr[e], sb = csr[e + 1];
    const float ha = h[(size_t)sa * EMB + c], hb = h[(size_t)sb * EMB + c];
    acc += ha * dinv[sa] + hb * dinv[sb];
  }
  if (e < s1) {
    const int sa = csr[e];
    acc += h[(size_t)sa * EMB + c] * dinv[sa];
  }
  out[(size_t)v * EMB + c] = acc * dv + bias[c];
}

// -------------------- fusion + Student-t soft assignment --------------------
__global__ void k_fuse(const float* __restrict__ zs, const float* __restrict__ zt,
                       const float* __restrict__ fw, const float* __restrict__ cent,
                       float* __restrict__ out_z, float* __restrict__ out_q) {
  const int v = blockIdx.x;
  const int t = threadIdx.x;  // 128
  __shared__ float zsh[EMB];
  __shared__ float cs[NC][EMB];
  __shared__ float qv[NC];
  __shared__ float qs;
  for (int k = t; k < NC * EMB; k += 128) ((float*)cs)[k] = cent[k];
  const float beta = 1.f / (1.f + expf(-fw[0]));
  const float z = beta * zs[(size_t)v * EMB + t] + (1.f - beta) * zt[(size_t)v * EMB + t];
  out_z[(size_t)v * EMB + t] = z;
  zsh[t] = z;
  __syncthreads();
  if (t < NC) {
    float s = 0.f;
    for (int c = 0; c < EMB; ++c) {
      const float d = zsh[c] - cs[t][c];
      s += d * d;
    }
    qv[t] = 1.f / (1.f + s);
  }
  __syncthreads();
  if (t == 0) {
    float s = 0.f;
    for (int k = 0; k < NC; ++k) s += qv[k];
    qs = s;
  }
  __syncthreads();
  if (t < NC) out_q[(size_t)v * NC + t] = qv[t] / qs;
}

extern "C" void kernel_launch(void* const* d_in, const int* in_sizes, int n_in, void* d_out,
                              int out_size, void* d_ws, size_t ws_size, hipStream_t stream) {
  const float* x = (const float*)d_in[0];
  const int* ei = (const int*)d_in[1];
  const float* W_s1 = (const float*)d_in[2];
  const float* b_s1 = (const float*)d_in[3];
  const float* W_s2 = (const float*)d_in[4];
  const float* b_s2 = (const float*)d_in[5];
  const float* W_t1 = (const float*)d_in[6];
  const float* b_t1 = (const float*)d_in[7];
  const float* W_t2 = (const float*)d_in[8];
  const float* b_t2 = (const float*)d_in[9];
  const float* fw = (const float*)d_in[10];
  const float* cent = (const float*)d_in[11];
  float* out_z = (float*)d_out;
  float* out_q = out_z + (size_t)N_NODES * EMB;

  char* w = (char*)d_ws;
  size_t o = 0;
  auto alloc = [&](size_t bytes) -> void* {
    void* p = w + o;
    o += (bytes + 255) & ~(size_t)255;
    return p;
  };
  // xnf (normalized f16, simgemm input) -> h1_s f32 after simgemm (both 10.24 MB)
  unsigned short* xnf = (unsigned short*)alloc((size_t)N_NODES * FEAT * 2);
  float* h1_s = (float*)xnf;
  // xf (raw f16, layer-1 GEMM input) -> h2_s/h2_t f32 after layer-1 GEMMs (10.24 MB)
  unsigned short* xf = (unsigned short*)alloc((size_t)N_NODES * FEAT * 2);
  float* h2_s = (float*)xf;
  float* h2_t = (float*)xf + (size_t)N_NODES * EMB;
  double* rinv = (double*)alloc((size_t)N_NODES * 8);
  // cap_buf (5.12 MB) -> r1_s f16 after k_knn (both 5.12 MB)
  unsigned int* cap_buf = (unsigned int*)alloc((size_t)N_NODES * CAP * 4);
  unsigned short* r1_s = (unsigned short*)cap_buf;
  unsigned short* r1_t = (unsigned short*)alloc((size_t)N_NODES * HID * 2);
  float* h1_t = (float*)alloc((size_t)N_NODES * HID * 4);
  float* z_s = (float*)alloc((size_t)N_NODES * EMB * 4);
  float* z_t = (float*)alloc((size_t)N_NODES * EMB * 4);
  int* nb = (int*)alloc((size_t)N_NODES * NNB * 4);
  int* cnt_s = (int*)alloc((size_t)N_NODES * 4);
  int* off_s = (int*)alloc((size_t)(N_NODES + 1) * 4);
  int* cur_s = (int*)alloc((size_t)N_NODES * 4);
  float* dinv_s = (float*)alloc((size_t)N_NODES * 4);
  int* cnt_t = (int*)alloc((size_t)N_NODES * 4);
  int* off_t = (int*)alloc((size_t)(N_NODES + 1) * 4);
  int* cur_t = (int*)alloc((size_t)N_NODES * 4);
  float* dinv_t = (float*)alloc((size_t)N_NODES * 4);
  int* csr_s = (int*)alloc((size_t)NE_EDGES * 4);
  int* csr_t = (int*)alloc((size_t)N_NODES * NNB * 4);
  int* cnt_row = (int*)alloc((size_t)N_NODES * 4);
  int* flags = (int*)alloc((size_t)N_NODES * 4);
  unsigned short* Wt_s1 = (unsigned short*)alloc((size_t)FEAT * HID * 2);
  unsigned short* Wt_t1 = (unsigned short*)alloc((size_t)FEAT * HID * 2);
  unsigned short* Wt_s2 = (unsigned short*)alloc((size_t)HID * EMB * 2);
  unsigned short* Wt_t2 = (unsigned short*)alloc((size_t)HID * EMB * 2);

  const int* e_src = ei;
  const int* e_dst = ei + NE_EDGES;

  // 1. norms -> f16 normalized + f16 raw + f64 inv norms; weight transposes
  k_norms<<<N_NODES, 128, 0, stream>>>(x, xnf, xf, rinv);
  k_wt<<<(FEAT * HID + 255) / 256, 256, 0, stream>>>(W_s1, Wt_s1, FEAT, HID);
  k_wt<<<(FEAT * HID + 255) / 256, 256, 0, stream>>>(W_t1, Wt_t1, FEAT, HID);
  k_wt<<<(HID * EMB + 255) / 256, 256, 0, stream>>>(W_s2, Wt_s2, HID, EMB);
  k_wt<<<(HID * EMB + 255) / 256, 256, 0, stream>>>(W_t2, Wt_t2, HID, EMB);
  // 2. zero counters
  k_zero<<<(N_NODES + 255) / 256, 256, 0, stream>>>(cnt_s, N_NODES);
  k_zero<<<(N_NODES + 255) / 256, 256, 0, stream>>>(cnt_t, N_NODES);
  k_zero<<<(N_NODES + 255) / 256, 256, 0, stream>>>(cnt_row, N_NODES);
  k_count<<<(NE_EDGES + 255) / 256, 256, 0, stream>>>(e_dst, NE_EDGES, cnt_s);
  // 3. sim GEMM (upper triangle, XCD-chunked, 3-stage ring) + threshold filter
  k_simgemm<<<NPAIR, 256, 0, stream>>>(xnf, cap_buf, cnt_row);
  // 4. fused select + exact f64 rescore -> 9 neighbors; fallback for flagged rows
  k_knn<<<N_NODES, 256, 0, stream>>>(x, rinv, cap_buf, cnt_row, nb, flags);
  k_fallback<<<N_NODES, 256, 0, stream>>>(x, rinv, flags, nb);
  // 5. topology degrees + scans + scatter
  k_count<<<(N_NODES * NNB + 255) / 256, 256, 0, stream>>>(nb, N_NODES * NNB, cnt_t);
  k_scan<<<1, 1024, 0, stream>>>(cnt_s, N_NODES, off_s, cur_s, dinv_s);
  k_scan<<<1, 1024, 0, stream>>>(cnt_t, N_NODES, off_t, cur_t, dinv_t);
  k_scatter_s<<<(NE_EDGES + 255) / 256, 256, 0, stream>>>(e_src, e_dst, NE_EDGES, cur_s, csr_s);
  k_scatter_t<<<(N_NODES * NNB + 255) / 256, 256, 0, stream>>>(nb, cur_t, csr_t);
  // 6. layer-1 f16 MFMA GEMMs, merged pair (h1_s aliases xnf: safe, simgemm done)
  {
    dim3 g1(NTB, 2 * (HID / 128));
    k_fgemm2<<<g1, 256, 0, stream>>>(xf, xf, Wt_s1, Wt_t1, h1_s, h1_t, N_NODES, FEAT, HID);
  }
  // 7. layer-1 aggregation + relu -> f16 r1 (r1_s overwrites cap_buf: safe, k_knn done)
  k_agg_h<<<N_NODES, HID, 0, stream>>>(h1_s, b_s1, dinv_s, off_s, csr_s, r1_s);
  k_agg_h<<<N_NODES, HID, 0, stream>>>(h1_t, b_t1, dinv_t, off_t, csr_t, r1_t);
  // 8. layer-2 f16 MFMA GEMMs, merged pair (h2_s/h2_t alias xf: safe, layer-1 GEMMs done)
  {
    dim3 g2(NTB, 2 * (EMB / 128));
    k_fgemm2<<<g2, 256, 0, stream>>>(r1_s, r1_t, Wt_s2, Wt_t2, h2_s, h2_t, N_NODES, HID, EMB);
  }
  // 9. layer-2 aggregation
  k_agg<<<N_NODES, EMB, 0, stream>>>(h2_s, b_s2, dinv_s, off_s, csr_s, z_s);
  k_agg<<<N_NODES, EMB, 0, stream>>>(h2_t, b_t2, dinv_t, off_t, csr_t, z_t);
  // 10. fusion + soft assignment
  k_fuse<<<N_NODES, 128, 0, stream>>>(z_s, z_t, fw, cent, out_z, out_q);
}